// Round 17
// baseline (278.078 us; speedup 1.0000x reference)
//
#include <hip/hip_runtime.h>
#include <hip/hip_bf16.h>

typedef short short8 __attribute__((ext_vector_type(8)));
typedef float f32x4  __attribute__((ext_vector_type(4)));

static constexpr int   NPB  = 16384;
static constexpr int   NR   = 4 * NPB;       // 65536 rays
static constexpr int   NS   = 16;
static constexpr int   H    = 128;
static constexpr int   NPTS = NR * NS;       // 1,048,576 march points
static constexpr int   NCHUNK = NPTS / 64;   // 16384 chunks of 64 points
static constexpr int   FIXCAP = 131072;
static constexpr float FARV = 2.4f;
static constexpr float EPSF = 1.1920928955078125e-07f;
// march f error with A=bf16-RNE only (W2 hi+lo): RMS ~1e-3, worst ~0.03.
// R9/R13 proved this config correctness-safe at FTHRESH=0.03.
static constexpr float FTHRESH = 0.03f;

// NOTE (R12): never declare __launch_bounds__ > 2 waves/EU on MFMA kernels —
// B-fragments need ~64 VGPRs; a tighter cap spills them (612 MB FETCH, 2x).
// NOTE (R14): refine groups must outnumber blocks (64-ray groups regressed).
// NOTE (R15): do NOT interleave stage1(c+1) VALU with stage2(c) MFMA — the
// allocator demotes B-fragments (VGPR 108->60, MfmaUtil down). Keep stages
// separated by the barrier; only unroll WITHIN stage 2.

// ---------------- bf16 helpers ---------------------------------------------
__device__ __forceinline__ unsigned bf16hi(float x) {
    unsigned u = __float_as_uint(x);
    return (u + 0x7FFFu + ((u >> 16) & 1u)) >> 16;
}
__device__ __forceinline__ void split_bf16(float x, short& hi, short& lo) {
    unsigned h = bf16hi(x);
    float hf = __uint_as_float(h << 16);
    unsigned l = __float_as_uint(x - hf) >> 16;
    hi = (short)h; lo = (short)l;
}
// packed RNE f32x2 -> bf16x2 (v_cvt_pk_bf16_f32 on gfx950)
__device__ __forceinline__ unsigned pk_bf16(float a, float b) {
    __hip_bfloat162 p = __float22bfloat162_rn(make_float2(a, b));
    unsigned u;
    __builtin_memcpy(&u, &p, sizeof(u));
    return u;
}

// DPP row-rotate sum over 16-lane rows (pure VALU pipe)
__device__ __forceinline__ float rowsum16(float v) {
    v += __int_as_float(__builtin_amdgcn_update_dpp(0, __float_as_int(v), 0x128, 0xF, 0xF, true));
    v += __int_as_float(__builtin_amdgcn_update_dpp(0, __float_as_int(v), 0x124, 0xF, 0xF, true));
    v += __int_as_float(__builtin_amdgcn_update_dpp(0, __float_as_int(v), 0x122, 0xF, 0xF, true));
    v += __int_as_float(__builtin_amdgcn_update_dpp(0, __float_as_int(v), 0x121, 0xF, 0xF, true));
    return v;
}

// ---------------- exact fp32 thread-per-point MLP (for fixups) -------------
__device__ __forceinline__ float mlp_eval(
    float px, float py, float pz,
    const float* __restrict__ W1, const float* __restrict__ cv,
    const float* __restrict__ W2, const float* __restrict__ b2,
    const float* __restrict__ W3, float b3v)
{
    float f = b3v;
#pragma unroll 1
    for (int p = 0; p < 2; ++p) {
        const float* __restrict__ b2p = b2 + p * 64;
        const float* __restrict__ W3p = W3 + p * 64;
        float a[64];
#pragma unroll
        for (int j = 0; j < 64; ++j) a[j] = b2p[j];
#pragma unroll 2
        for (int k = 0; k < H; ++k) {
            float hk = cv[k];
            hk = fmaf(px, W1[k], hk);
            hk = fmaf(py, W1[H + k], hk);
            hk = fmaf(pz, W1[2 * H + k], hk);
            hk = fmaxf(hk, 0.0f);
            const float* __restrict__ w = W2 + k * H + p * 64;
#pragma unroll
            for (int j = 0; j < 64; ++j) a[j] = fmaf(hk, w[j], a[j]);
        }
#pragma unroll
        for (int j = 0; j < 64; ++j)
            f = fmaf(fmaxf(a[j], 0.0f), W3p[j], f);
    }
    return f;
}

// ---------------- setup: cv vectors + W2 MFMA packing + counters -----------
__global__ void k_setup(const float* __restrict__ W1, const float* __restrict__ b1,
                        const float* __restrict__ W2, const float* __restrict__ feat,
                        float* __restrict__ cva, short* __restrict__ w2f,
                        int* __restrict__ count, int* __restrict__ fixcnt)
{
    int t = blockIdx.x * blockDim.x + threadIdx.x;   // 4096 threads
    if (t == 0) { *count = 0; *fixcnt = 0; }
    if (t < 4 * H) {                                 // cv = b1 + feat @ W1[3:35]
        int b = t >> 7, kk = t & (H - 1);
        float acc = b1[kk];
#pragma unroll
        for (int i = 0; i < 32; ++i)
            acc = fmaf(feat[b * 32 + i], W1[(3 + i) * H + kk], acc);
        cva[b * H + kk] = acc;
    }
    {                                                // MFMA B-fragments (hi/lo)
        int lane = t & 63, ks = (t >> 6) & 3, part = (t >> 8) & 1;
        int nt = (t >> 9) & 1, w = (t >> 10) & 3;
        int n = w * 32 + nt * 16 + (lane & 15);
        int kb = ks * 32 + (lane >> 4) * 8;
        short8 v;
#pragma unroll
        for (int j = 0; j < 8; ++j) {
            short hi, lo;
            split_bf16(W2[(kb + j) * H + n], hi, lo);
            v[j] = part ? lo : hi;
        }
        ((short8*)w2f)[((w * 4 + nt * 2 + part) * 4 + ks) * 64 + lane] = v;
    }
}

// ---------------- Phase A: MFMA march (64 points per chunk) ----------------
// R13 structure + (R17) fpart ping-pong (2 barriers/chunk, was 3) and
// unroll-2 on the mt loop (2 independent MFMA chains per scheduling region).
__global__ __launch_bounds__(256, 2) void k_marchx(
    const float* __restrict__ ray0, const float* __restrict__ dirs,
    const float* __restrict__ W1,   const float* __restrict__ cva,
    const float* __restrict__ b2,   const float* __restrict__ W3,
    const float* __restrict__ b3p,  const short* __restrict__ w2f,
    float* __restrict__ f_all, int* __restrict__ fixlist, int* __restrict__ fixcnt)
{
    __shared__ __align__(16) short hAhi[8192];       // 64 pts x 128 k (16 KB)
    __shared__ float fpart[2][4][64];                // ping-pong (drops barrier 3)
    const int tid = threadIdx.x;
    const int w = tid >> 6, lane = tid & 63;
    const int q = lane >> 4, ln15 = lane & 15;

    const short8* wf8 = (const short8*)w2f;
    short8 Bh0[4], Bl0[4], Bh1[4], Bl1[4];
#pragma unroll
    for (int ks = 0; ks < 4; ++ks) {
        Bh0[ks] = wf8[((w * 4 + 0) * 4 + ks) * 64 + lane];
        Bl0[ks] = wf8[((w * 4 + 1) * 4 + ks) * 64 + lane];
        Bh1[ks] = wf8[((w * 4 + 2) * 4 + ks) * 64 + lane];
        Bl1[ks] = wf8[((w * 4 + 3) * 4 + ks) * 64 + lane];
    }
    const float w3n0 = W3[w * 32 + ln15],      w3n1 = W3[w * 32 + 16 + ln15];
    const float b2n0 = b2[w * 32 + ln15],      b2n1 = b2[w * 32 + 16 + ln15];
    const float b3v  = *b3p;

    int pp = 0;
    for (int c = blockIdx.x; c < NCHUNK; c += gridDim.x) {
        // ---- stage 1: h (fp32) -> RNE bf16 -> LDS in A-frag order
        {
            int m = w * 16 + ln15;
            int P = c * 64 + m;
            int r = P & (NR - 1), s = P >> 16;
            float d = ((float)s * (1.0f / 15.0f)) * FARV;
            float ox = ray0[3 * r], oy = ray0[3 * r + 1], oz = ray0[3 * r + 2];
            float dx = dirs[3 * r], dy = dirs[3 * r + 1], dz = dirs[3 * r + 2];
            float px = fmaf(d, dx, ox), py = fmaf(d, dy, oy), pz = fmaf(d, dz, oz);
            const float4* W1x4 = (const float4*)(W1);
            const float4* W1y4 = (const float4*)(W1 + H);
            const float4* W1z4 = (const float4*)(W1 + 2 * H);
            const float4* cv4  = (const float4*)(cva + (((c * 64) & (NR - 1)) >> 14) * H);
            uint4* hi4 = (uint4*)hAhi;
#pragma unroll
            for (int ks = 0; ks < 4; ++ks) {
                int i4 = (ks * 32 + q * 8) >> 2;
                float4 x0 = W1x4[i4], x1 = W1x4[i4 + 1];
                float4 y0 = W1y4[i4], y1 = W1y4[i4 + 1];
                float4 z0 = W1z4[i4], z1 = W1z4[i4 + 1];
                float4 c0 = cv4[i4],  c1 = cv4[i4 + 1];
                float hv[8];
                hv[0] = fmaf(px, x0.x, fmaf(py, y0.x, fmaf(pz, z0.x, c0.x)));
                hv[1] = fmaf(px, x0.y, fmaf(py, y0.y, fmaf(pz, z0.y, c0.y)));
                hv[2] = fmaf(px, x0.z, fmaf(py, y0.z, fmaf(pz, z0.z, c0.z)));
                hv[3] = fmaf(px, x0.w, fmaf(py, y0.w, fmaf(pz, z0.w, c0.w)));
                hv[4] = fmaf(px, x1.x, fmaf(py, y1.x, fmaf(pz, z1.x, c1.x)));
                hv[5] = fmaf(px, x1.y, fmaf(py, y1.y, fmaf(pz, z1.y, c1.y)));
                hv[6] = fmaf(px, x1.z, fmaf(py, y1.z, fmaf(pz, z1.z, c1.z)));
                hv[7] = fmaf(px, x1.w, fmaf(py, y1.w, fmaf(pz, z1.w, c1.w)));
                unsigned uh[4];
#pragma unroll
                for (int jp = 0; jp < 4; ++jp)
                    uh[jp] = pk_bf16(fmaxf(hv[2 * jp],     0.0f),
                                     fmaxf(hv[2 * jp + 1], 0.0f));
                hi4[(w * 4 + ks) * 64 + lane] = make_uint4(uh[0], uh[1], uh[2], uh[3]);
            }
        }
        __syncthreads();
        // ---- stage 2: MFMA per 16-point M-tile + epilogue (unroll 2)
        const short8* hi8 = (const short8*)hAhi;
#pragma unroll 2
        for (int mt = 0; mt < 4; ++mt) {
            short8 Ah[4];
#pragma unroll
            for (int ks = 0; ks < 4; ++ks)
                Ah[ks] = hi8[(mt * 4 + ks) * 64 + lane];
            f32x4 a0 = {0.f, 0.f, 0.f, 0.f}, a1 = {0.f, 0.f, 0.f, 0.f};
#pragma unroll
            for (int ks = 0; ks < 4; ++ks) {
                a0 = __builtin_amdgcn_mfma_f32_16x16x32_bf16(Ah[ks], Bh0[ks], a0, 0, 0, 0);
                a1 = __builtin_amdgcn_mfma_f32_16x16x32_bf16(Ah[ks], Bh1[ks], a1, 0, 0, 0);
                a0 = __builtin_amdgcn_mfma_f32_16x16x32_bf16(Ah[ks], Bl0[ks], a0, 0, 0, 0);
                a1 = __builtin_amdgcn_mfma_f32_16x16x32_bf16(Ah[ks], Bl1[ks], a1, 0, 0, 0);
            }
#pragma unroll
            for (int reg = 0; reg < 4; ++reg) {
                float v = fmaf(fmaxf(a0[reg] + b2n0, 0.f), w3n0,
                               fmaxf(a1[reg] + b2n1, 0.f) * w3n1);
                v = rowsum16(v);
                if (ln15 == 0) fpart[pp][w][mt * 16 + q * 4 + reg] = v;
            }
        }
        __syncthreads();
        // ---- stage 3: finalize 64 points, flag near-zero f for fp32 fixup.
        // fpart[pp] is not rewritten until two barriers from now (ping-pong),
        // so no trailing barrier is needed.
        if (tid < 64) {
            float f = fpart[pp][0][tid] + fpart[pp][1][tid] + fpart[pp][2][tid]
                    + fpart[pp][3][tid] + b3v;
            int P = c * 64 + tid;
            f_all[P] = f;
            if (fabsf(f) < FTHRESH) {
                int s = atomicAdd(fixcnt, 1);
                if (s < FIXCAP) fixlist[s] = P;
            }
        }
        pp ^= 1;
    }
}

// ---------------- fp32 re-eval of near-zero points -------------------------
__global__ __launch_bounds__(256, 2) void k_fix(
    const float* __restrict__ ray0, const float* __restrict__ dirs,
    const float* __restrict__ W1,   const float* __restrict__ cva,
    const float* __restrict__ W2,   const float* __restrict__ b2,
    const float* __restrict__ W3,   const float* __restrict__ b3p,
    const int* __restrict__ fixcnt, const int* __restrict__ fixlist,
    float* __restrict__ f_all)
{
    int t = blockIdx.x * blockDim.x + threadIdx.x;
    unsigned fc = (unsigned)*fixcnt;
    if (fc > (unsigned)FIXCAP) fc = FIXCAP;
    if ((unsigned)t >= fc) return;
    int P = fixlist[t] & (NPTS - 1);
    int r = P & (NR - 1), s = P >> 16;
    float d = ((float)s * (1.0f / 15.0f)) * FARV;
    float ox = ray0[3 * r], oy = ray0[3 * r + 1], oz = ray0[3 * r + 2];
    float dx = dirs[3 * r], dy = dirs[3 * r + 1], dz = dirs[3 * r + 2];
    const float* cv = cva + (r >> 14) * H;
    f_all[P] = mlp_eval(fmaf(d, dx, ox), fmaf(d, dy, oy), fmaf(d, dz, oz),
                        W1, cv, W2, b2, W3, *b3p);
}

// ---------------- crossing scan --------------------------------------------
__global__ void k_cross(
    const float* __restrict__ ray0, const float* __restrict__ dirs,
    const float* __restrict__ f_all,
    int* __restrict__ count, int* __restrict__ ids,
    float4* __restrict__ state, float* __restrict__ out)
{
    int r = blockIdx.x * blockDim.x + threadIdx.x;   // 65536 threads
    float fv[NS];
#pragma unroll
    for (int s = 0; s < NS; ++s) fv[s] = f_all[s * NR + r];
    int idx = -1;
#pragma unroll
    for (int s = NS - 2; s >= 0; --s) {
        if (fv[s] < 0.0f && fv[s + 1] >= 0.0f) idx = s;
    }
    if (idx < 0) {
        float ox = ray0[3 * r], oy = ray0[3 * r + 1], oz = ray0[3 * r + 2];
        float dx = dirs[3 * r], dy = dirs[3 * r + 1], dz = dirs[3 * r + 2];
        out[r] = FARV;
        out[NR + 3 * r + 0] = fmaf(FARV, dx, ox);
        out[NR + 3 * r + 1] = fmaf(FARV, dy, oy);
        out[NR + 3 * r + 2] = fmaf(FARV, dz, oz);
        out[4 * NR + r] = 0.0f;
    } else {
        int slot = atomicAdd(count, 1);
        ids[slot] = r;
        float dlo = ((float)idx * (1.0f / 15.0f)) * FARV;
        float dhi = ((float)(idx + 1) * (1.0f / 15.0f)) * FARV;
        state[slot] = make_float4(dlo, 0.0f, dhi, 0.0f);   // f re-evaled in refine
    }
}

// ---------------- Phase B: MFMA secant refine (16 rays per block) ----------
// R13 version (proven). 6-MFMA eval (err ~3e-5); brackets re-evaluated here
// (it=0,1). Grid 1280: ~1250 groups map ~1:1 to blocks, 4-5 blocks/CU.
__global__ __launch_bounds__(256, 2) void k_refine(
    const float* __restrict__ ray0, const float* __restrict__ dirs,
    const float* __restrict__ W1,   const float* __restrict__ cva,
    const float* __restrict__ b2,   const float* __restrict__ W3,
    const float* __restrict__ b3p,  const short* __restrict__ w2f,
    const int* __restrict__ count,  const int* __restrict__ ids,
    const float4* __restrict__ state, float* __restrict__ out)
{
    __shared__ __align__(16) short hAhi[2048];       // 4 ks x 64 lanes x short8
    __shared__ __align__(16) short hAlo[2048];
    __shared__ float fpart[4][16];
    const int tid = threadIdx.x;
    const int w = tid >> 6, lane = tid & 63;
    const int q = lane >> 4, ln15 = lane & 15;

    unsigned cnt = (unsigned)*count;
    if (cnt > (unsigned)NR) cnt = (unsigned)NR;      // poison guard

    const short8* wf8 = (const short8*)w2f;
    short8 Bh0[4], Bl0[4], Bh1[4], Bl1[4];
#pragma unroll
    for (int ks = 0; ks < 4; ++ks) {
        Bh0[ks] = wf8[((w * 4 + 0) * 4 + ks) * 64 + lane];
        Bl0[ks] = wf8[((w * 4 + 1) * 4 + ks) * 64 + lane];
        Bh1[ks] = wf8[((w * 4 + 2) * 4 + ks) * 64 + lane];
        Bl1[ks] = wf8[((w * 4 + 3) * 4 + ks) * 64 + lane];
    }
    const float w3n0 = W3[w * 32 + ln15],      w3n1 = W3[w * 32 + 16 + ln15];
    const float b2n0 = b2[w * 32 + ln15],      b2n1 = b2[w * 32 + 16 + ln15];
    const float b3v  = *b3p;

    const int i4 = (w * 32 + q * 8) >> 2;
    const float4* W1x4 = (const float4*)(W1);
    const float4* W1y4 = (const float4*)(W1 + H);
    const float4* W1z4 = (const float4*)(W1 + 2 * H);
    const float4 x0 = W1x4[i4], x1 = W1x4[i4 + 1];
    const float4 y0 = W1y4[i4], y1 = W1y4[i4 + 1];
    const float4 z0 = W1z4[i4], z1 = W1z4[i4 + 1];

    uint4* hi4 = (uint4*)hAhi;
    uint4* lo4 = (uint4*)hAlo;
    const short8* hi8 = (const short8*)hAhi;
    const short8* lo8 = (const short8*)hAlo;

    for (unsigned g = blockIdx.x; g * 16u < cnt; g += gridDim.x) {
        unsigned t = g * 16u + (unsigned)ln15;
        bool valid = (t < cnt);
        unsigned tc = valid ? t : (cnt - 1);
        int r = ids[tc] & (NR - 1);                  // poison guard
        float4 st = state[tc];
        float dlo = st.x, dhi = st.z;
        float flo = 0.0f, fhi = 0.0f;
        float ox = ray0[3 * r], oy = ray0[3 * r + 1], oz = ray0[3 * r + 2];
        float dx = dirs[3 * r], dy = dirs[3 * r + 1], dz = dirs[3 * r + 2];
        const float4* cv4 = (const float4*)(cva + (r >> 14) * H);
        float4 c0 = cv4[i4], c1 = cv4[i4 + 1];
        float dp = 0.0f;

#pragma unroll 1
        for (int it = 0; it < 11; ++it) {
            // it 0: eval @dlo; it 1: eval @dhi; it 2..9: secant; it 10: final
            float dn;
            if (it >= 2) {
                float dc  = fhi - flo;
                float den = copysignf(fmaxf(fabsf(dc), EPSF), dc);
                dn  = dlo - (flo * (dhi - dlo)) / den;
                if (it == 10) { dp = dn; break; }
            } else {
                dn = (it == 0) ? dlo : dhi;
            }
            // stage 1: h for ray ln15, 8 k values -> hi/lo bf16 -> LDS
            float px = fmaf(dn, dx, ox), py = fmaf(dn, dy, oy), pz = fmaf(dn, dz, oz);
            float hv[8];
            hv[0] = fmaf(px, x0.x, fmaf(py, y0.x, fmaf(pz, z0.x, c0.x)));
            hv[1] = fmaf(px, x0.y, fmaf(py, y0.y, fmaf(pz, z0.y, c0.y)));
            hv[2] = fmaf(px, x0.z, fmaf(py, y0.z, fmaf(pz, z0.z, c0.z)));
            hv[3] = fmaf(px, x0.w, fmaf(py, y0.w, fmaf(pz, z0.w, c0.w)));
            hv[4] = fmaf(px, x1.x, fmaf(py, y1.x, fmaf(pz, z1.x, c1.x)));
            hv[5] = fmaf(px, x1.y, fmaf(py, y1.y, fmaf(pz, z1.y, c1.y)));
            hv[6] = fmaf(px, x1.z, fmaf(py, y1.z, fmaf(pz, z1.z, c1.z)));
            hv[7] = fmaf(px, x1.w, fmaf(py, y1.w, fmaf(pz, z1.w, c1.w)));
            unsigned uh[4], ul[4];
#pragma unroll
            for (int jp = 0; jp < 4; ++jp) {
                float h0 = fmaxf(hv[2 * jp],     0.0f);
                float h1 = fmaxf(hv[2 * jp + 1], 0.0f);
                unsigned u = pk_bf16(h0, h1);
                float hf0 = __uint_as_float(u << 16);
                float hf1 = __uint_as_float(u & 0xFFFF0000u);
                ul[jp] = pk_bf16(h0 - hf0, h1 - hf1);
                uh[jp] = u;
            }
            hi4[w * 64 + lane] = make_uint4(uh[0], uh[1], uh[2], uh[3]);
            lo4[w * 64 + lane] = make_uint4(ul[0], ul[1], ul[2], ul[3]);
            __syncthreads();
            // stage 2: MFMA (single 16-ray M-tile) + epilogue
            short8 Ah[4], Al[4];
#pragma unroll
            for (int ks = 0; ks < 4; ++ks) {
                Ah[ks] = hi8[ks * 64 + lane];
                Al[ks] = lo8[ks * 64 + lane];
            }
            f32x4 a0 = {0.f, 0.f, 0.f, 0.f}, a1 = {0.f, 0.f, 0.f, 0.f};
#pragma unroll
            for (int ks = 0; ks < 4; ++ks) {
                a0 = __builtin_amdgcn_mfma_f32_16x16x32_bf16(Ah[ks], Bh0[ks], a0, 0, 0, 0);
                a1 = __builtin_amdgcn_mfma_f32_16x16x32_bf16(Ah[ks], Bh1[ks], a1, 0, 0, 0);
                a0 = __builtin_amdgcn_mfma_f32_16x16x32_bf16(Al[ks], Bh0[ks], a0, 0, 0, 0);
                a1 = __builtin_amdgcn_mfma_f32_16x16x32_bf16(Al[ks], Bh1[ks], a1, 0, 0, 0);
                a0 = __builtin_amdgcn_mfma_f32_16x16x32_bf16(Ah[ks], Bl0[ks], a0, 0, 0, 0);
                a1 = __builtin_amdgcn_mfma_f32_16x16x32_bf16(Ah[ks], Bl1[ks], a1, 0, 0, 0);
            }
#pragma unroll
            for (int reg = 0; reg < 4; ++reg) {
                float v = fmaf(fmaxf(a0[reg] + b2n0, 0.f), w3n0,
                               fmaxf(a1[reg] + b2n1, 0.f) * w3n1);
                v = rowsum16(v);
                if (ln15 == 0) fpart[w][q * 4 + reg] = v;
            }
            __syncthreads();
            float fn = fpart[0][ln15] + fpart[1][ln15] + fpart[2][ln15]
                     + fpart[3][ln15] + b3v;
            if (it == 0)      { flo = fn; }
            else if (it == 1) { fhi = fn; }
            else {
                bool bel = (fn < 0.0f);
                dlo = bel ? dn  : dlo;  flo = bel ? fn  : flo;
                dhi = bel ? dhi : dn;   fhi = bel ? fhi : fn;
            }
        }
        if (tid < 16 && valid) {
            out[r] = dp;
            out[NR + 3 * r + 0] = fmaf(dp, dx, ox);
            out[NR + 3 * r + 1] = fmaf(dp, dy, oy);
            out[NR + 3 * r + 2] = fmaf(dp, dz, oz);
            out[4 * NR + r] = 1.0f;
        }
    }
}

// ---------------------------------------------------------------------------
extern "C" void kernel_launch(void* const* d_in, const int* in_sizes, int n_in,
                              void* d_out, int out_size, void* d_ws, size_t ws_size,
                              hipStream_t stream)
{
    const float* ray0 = (const float*)d_in[0];
    const float* dirs = (const float*)d_in[1];
    const float* feat = (const float*)d_in[2];
    const float* W1   = (const float*)d_in[3];
    const float* b1   = (const float*)d_in[4];
    const float* W2   = (const float*)d_in[5];
    const float* b2   = (const float*)d_in[6];
    const float* W3   = (const float*)d_in[7];
    const float* b3   = (const float*)d_in[8];
    float* out = (float*)d_out;

    // workspace layout (float offsets), total ~6.1 MB
    float* w      = (float*)d_ws;
    short* w2f    = (short*)w;                        // 32768 bf16 = 16384 f
    float* cva    = w + 16384;                        // 512
    float* f_all  = w + 16896;                        // 1,048,576
    float* stf    = w + 1065472;                      // 262,144 (16B aligned)
    int*   ids    = (int*)(w + 1327616);              // 65,536
    int*   fixlist= (int*)(w + 1393152);              // 131,072
    int*   count  = (int*)(w + 1524224);
    int*   fixcnt = (int*)(w + 1524225);

    k_setup <<<16,   256, 0, stream>>>(W1, b1, W2, feat, cva, w2f, count, fixcnt);
    k_marchx<<<512,  256, 0, stream>>>(ray0, dirs, W1, cva, b2, W3, b3, w2f,
                                       f_all, fixlist, fixcnt);
    k_fix   <<<FIXCAP / 256, 256, 0, stream>>>(ray0, dirs, W1, cva, W2, b2, W3, b3,
                                               fixcnt, fixlist, f_all);
    k_cross <<<NR / 256, 256, 0, stream>>>(ray0, dirs, f_all, count, ids,
                                           (float4*)stf, out);
    k_refine<<<1280, 256, 0, stream>>>(ray0, dirs, W1, cva, b2, W3, b3, w2f,
                                       count, ids, (const float4*)stf, out);
}

// Round 18
// 276.968 us; speedup vs baseline: 1.0040x; 1.0040x over previous
//
#include <hip/hip_runtime.h>
#include <hip/hip_bf16.h>

typedef short short8 __attribute__((ext_vector_type(8)));
typedef float f32x4  __attribute__((ext_vector_type(4)));

static constexpr int   NPB  = 16384;
static constexpr int   NR   = 4 * NPB;       // 65536 rays
static constexpr int   NS   = 16;
static constexpr int   H    = 128;
static constexpr int   NPTS = NR * NS;       // 1,048,576 march points
static constexpr int   NCHUNK = NPTS / 64;   // 16384 chunks of 64 points
static constexpr int   FIXCAP = 131072;
static constexpr float FARV = 2.4f;
static constexpr float EPSF = 1.1920928955078125e-07f;
// march f error with A=bf16-RNE only (W2 hi+lo): RMS ~1e-3, worst ~0.03.
// R9/R13 proved this config correctness-safe at FTHRESH=0.03.
static constexpr float FTHRESH = 0.03f;

// NOTE (R12): never declare __launch_bounds__ > 2 waves/EU on MFMA kernels.
// NOTE (R14): refine groups must outnumber blocks.
// NOTE (R15): do NOT interleave stage1(c+1) VALU with stage2(c) MFMA.
// NOTE (R17): extra barrier removal / mt-unroll are neutral — compiler
// schedule was already optimal; marchx residual idle is barrier-drain.

// ---------------- bf16 helpers ---------------------------------------------
__device__ __forceinline__ unsigned bf16hi(float x) {
    unsigned u = __float_as_uint(x);
    return (u + 0x7FFFu + ((u >> 16) & 1u)) >> 16;
}
__device__ __forceinline__ void split_bf16(float x, short& hi, short& lo) {
    unsigned h = bf16hi(x);
    float hf = __uint_as_float(h << 16);
    unsigned l = __float_as_uint(x - hf) >> 16;
    hi = (short)h; lo = (short)l;
}
// packed RNE f32x2 -> bf16x2 (v_cvt_pk_bf16_f32 on gfx950)
__device__ __forceinline__ unsigned pk_bf16(float a, float b) {
    __hip_bfloat162 p = __float22bfloat162_rn(make_float2(a, b));
    unsigned u;
    __builtin_memcpy(&u, &p, sizeof(u));
    return u;
}

// DPP row-rotate sum over 16-lane rows (pure VALU pipe)
__device__ __forceinline__ float rowsum16(float v) {
    v += __int_as_float(__builtin_amdgcn_update_dpp(0, __float_as_int(v), 0x128, 0xF, 0xF, true));
    v += __int_as_float(__builtin_amdgcn_update_dpp(0, __float_as_int(v), 0x124, 0xF, 0xF, true));
    v += __int_as_float(__builtin_amdgcn_update_dpp(0, __float_as_int(v), 0x122, 0xF, 0xF, true));
    v += __int_as_float(__builtin_amdgcn_update_dpp(0, __float_as_int(v), 0x121, 0xF, 0xF, true));
    return v;
}

// ---------------- exact fp32 thread-per-point MLP (for fixups) -------------
__device__ __forceinline__ float mlp_eval(
    float px, float py, float pz,
    const float* __restrict__ W1, const float* __restrict__ cv,
    const float* __restrict__ W2, const float* __restrict__ b2,
    const float* __restrict__ W3, float b3v)
{
    float f = b3v;
#pragma unroll 1
    for (int p = 0; p < 2; ++p) {
        const float* __restrict__ b2p = b2 + p * 64;
        const float* __restrict__ W3p = W3 + p * 64;
        float a[64];
#pragma unroll
        for (int j = 0; j < 64; ++j) a[j] = b2p[j];
#pragma unroll 2
        for (int k = 0; k < H; ++k) {
            float hk = cv[k];
            hk = fmaf(px, W1[k], hk);
            hk = fmaf(py, W1[H + k], hk);
            hk = fmaf(pz, W1[2 * H + k], hk);
            hk = fmaxf(hk, 0.0f);
            const float* __restrict__ w = W2 + k * H + p * 64;
#pragma unroll
            for (int j = 0; j < 64; ++j) a[j] = fmaf(hk, w[j], a[j]);
        }
#pragma unroll
        for (int j = 0; j < 64; ++j)
            f = fmaf(fmaxf(a[j], 0.0f), W3p[j], f);
    }
    return f;
}

// ---------------- setup: cv vectors + W2 MFMA packing + counters -----------
__global__ void k_setup(const float* __restrict__ W1, const float* __restrict__ b1,
                        const float* __restrict__ W2, const float* __restrict__ feat,
                        float* __restrict__ cva, short* __restrict__ w2f,
                        int* __restrict__ count, int* __restrict__ fixcnt)
{
    int t = blockIdx.x * blockDim.x + threadIdx.x;   // 4096 threads
    if (t == 0) { *count = 0; *fixcnt = 0; }
    if (t < 4 * H) {                                 // cv = b1 + feat @ W1[3:35]
        int b = t >> 7, kk = t & (H - 1);
        float acc = b1[kk];
#pragma unroll
        for (int i = 0; i < 32; ++i)
            acc = fmaf(feat[b * 32 + i], W1[(3 + i) * H + kk], acc);
        cva[b * H + kk] = acc;
    }
    {                                                // MFMA B-fragments (hi/lo)
        int lane = t & 63, ks = (t >> 6) & 3, part = (t >> 8) & 1;
        int nt = (t >> 9) & 1, w = (t >> 10) & 3;
        int n = w * 32 + nt * 16 + (lane & 15);
        int kb = ks * 32 + (lane >> 4) * 8;
        short8 v;
#pragma unroll
        for (int j = 0; j < 8; ++j) {
            short hi, lo;
            split_bf16(W2[(kb + j) * H + n], hi, lo);
            v[j] = part ? lo : hi;
        }
        ((short8*)w2f)[((w * 4 + nt * 2 + part) * 4 + ks) * 64 + lane] = v;
    }
}

// ---------------- Phase A: MFMA march (64 points per chunk) ----------------
// R13-proven structure. A = bf16-RNE only; W2 = hi+lo -> 4 MFMAs per (mt,ks).
__global__ __launch_bounds__(256, 2) void k_marchx(
    const float* __restrict__ ray0, const float* __restrict__ dirs,
    const float* __restrict__ W1,   const float* __restrict__ cva,
    const float* __restrict__ b2,   const float* __restrict__ W3,
    const float* __restrict__ b3p,  const short* __restrict__ w2f,
    float* __restrict__ f_all, int* __restrict__ fixlist, int* __restrict__ fixcnt)
{
    __shared__ __align__(16) short hAhi[8192];       // 64 pts x 128 k (16 KB)
    __shared__ float fpart[2][4][64];                // ping-pong
    const int tid = threadIdx.x;
    const int w = tid >> 6, lane = tid & 63;
    const int q = lane >> 4, ln15 = lane & 15;

    const short8* wf8 = (const short8*)w2f;
    short8 Bh0[4], Bl0[4], Bh1[4], Bl1[4];
#pragma unroll
    for (int ks = 0; ks < 4; ++ks) {
        Bh0[ks] = wf8[((w * 4 + 0) * 4 + ks) * 64 + lane];
        Bl0[ks] = wf8[((w * 4 + 1) * 4 + ks) * 64 + lane];
        Bh1[ks] = wf8[((w * 4 + 2) * 4 + ks) * 64 + lane];
        Bl1[ks] = wf8[((w * 4 + 3) * 4 + ks) * 64 + lane];
    }
    const float w3n0 = W3[w * 32 + ln15],      w3n1 = W3[w * 32 + 16 + ln15];
    const float b2n0 = b2[w * 32 + ln15],      b2n1 = b2[w * 32 + 16 + ln15];
    const float b3v  = *b3p;

    int pp = 0;
    for (int c = blockIdx.x; c < NCHUNK; c += gridDim.x) {
        // ---- stage 1: h (fp32) -> RNE bf16 -> LDS in A-frag order
        {
            int m = w * 16 + ln15;
            int P = c * 64 + m;
            int r = P & (NR - 1), s = P >> 16;
            float d = ((float)s * (1.0f / 15.0f)) * FARV;
            float ox = ray0[3 * r], oy = ray0[3 * r + 1], oz = ray0[3 * r + 2];
            float dx = dirs[3 * r], dy = dirs[3 * r + 1], dz = dirs[3 * r + 2];
            float px = fmaf(d, dx, ox), py = fmaf(d, dy, oy), pz = fmaf(d, dz, oz);
            const float4* W1x4 = (const float4*)(W1);
            const float4* W1y4 = (const float4*)(W1 + H);
            const float4* W1z4 = (const float4*)(W1 + 2 * H);
            const float4* cv4  = (const float4*)(cva + (((c * 64) & (NR - 1)) >> 14) * H);
            uint4* hi4 = (uint4*)hAhi;
#pragma unroll
            for (int ks = 0; ks < 4; ++ks) {
                int i4 = (ks * 32 + q * 8) >> 2;
                float4 x0 = W1x4[i4], x1 = W1x4[i4 + 1];
                float4 y0 = W1y4[i4], y1 = W1y4[i4 + 1];
                float4 z0 = W1z4[i4], z1 = W1z4[i4 + 1];
                float4 c0 = cv4[i4],  c1 = cv4[i4 + 1];
                float hv[8];
                hv[0] = fmaf(px, x0.x, fmaf(py, y0.x, fmaf(pz, z0.x, c0.x)));
                hv[1] = fmaf(px, x0.y, fmaf(py, y0.y, fmaf(pz, z0.y, c0.y)));
                hv[2] = fmaf(px, x0.z, fmaf(py, y0.z, fmaf(pz, z0.z, c0.z)));
                hv[3] = fmaf(px, x0.w, fmaf(py, y0.w, fmaf(pz, z0.w, c0.w)));
                hv[4] = fmaf(px, x1.x, fmaf(py, y1.x, fmaf(pz, z1.x, c1.x)));
                hv[5] = fmaf(px, x1.y, fmaf(py, y1.y, fmaf(pz, z1.y, c1.y)));
                hv[6] = fmaf(px, x1.z, fmaf(py, y1.z, fmaf(pz, z1.z, c1.z)));
                hv[7] = fmaf(px, x1.w, fmaf(py, y1.w, fmaf(pz, z1.w, c1.w)));
                unsigned uh[4];
#pragma unroll
                for (int jp = 0; jp < 4; ++jp)
                    uh[jp] = pk_bf16(fmaxf(hv[2 * jp],     0.0f),
                                     fmaxf(hv[2 * jp + 1], 0.0f));
                hi4[(w * 4 + ks) * 64 + lane] = make_uint4(uh[0], uh[1], uh[2], uh[3]);
            }
        }
        __syncthreads();
        // ---- stage 2: MFMA per 16-point M-tile + epilogue
        const short8* hi8 = (const short8*)hAhi;
#pragma unroll 2
        for (int mt = 0; mt < 4; ++mt) {
            short8 Ah[4];
#pragma unroll
            for (int ks = 0; ks < 4; ++ks)
                Ah[ks] = hi8[(mt * 4 + ks) * 64 + lane];
            f32x4 a0 = {0.f, 0.f, 0.f, 0.f}, a1 = {0.f, 0.f, 0.f, 0.f};
#pragma unroll
            for (int ks = 0; ks < 4; ++ks) {
                a0 = __builtin_amdgcn_mfma_f32_16x16x32_bf16(Ah[ks], Bh0[ks], a0, 0, 0, 0);
                a1 = __builtin_amdgcn_mfma_f32_16x16x32_bf16(Ah[ks], Bh1[ks], a1, 0, 0, 0);
                a0 = __builtin_amdgcn_mfma_f32_16x16x32_bf16(Ah[ks], Bl0[ks], a0, 0, 0, 0);
                a1 = __builtin_amdgcn_mfma_f32_16x16x32_bf16(Ah[ks], Bl1[ks], a1, 0, 0, 0);
            }
#pragma unroll
            for (int reg = 0; reg < 4; ++reg) {
                float v = fmaf(fmaxf(a0[reg] + b2n0, 0.f), w3n0,
                               fmaxf(a1[reg] + b2n1, 0.f) * w3n1);
                v = rowsum16(v);
                if (ln15 == 0) fpart[pp][w][mt * 16 + q * 4 + reg] = v;
            }
        }
        __syncthreads();
        // ---- stage 3: finalize 64 points (fpart ping-pong: no 3rd barrier)
        if (tid < 64) {
            float f = fpart[pp][0][tid] + fpart[pp][1][tid] + fpart[pp][2][tid]
                    + fpart[pp][3][tid] + b3v;
            int P = c * 64 + tid;
            f_all[P] = f;
            if (fabsf(f) < FTHRESH) {
                int s = atomicAdd(fixcnt, 1);
                if (s < FIXCAP) fixlist[s] = P;
            }
        }
        pp ^= 1;
    }
}

// ---------------- fp32 re-eval of near-zero points -------------------------
__global__ __launch_bounds__(256, 2) void k_fix(
    const float* __restrict__ ray0, const float* __restrict__ dirs,
    const float* __restrict__ W1,   const float* __restrict__ cva,
    const float* __restrict__ W2,   const float* __restrict__ b2,
    const float* __restrict__ W3,   const float* __restrict__ b3p,
    const int* __restrict__ fixcnt, const int* __restrict__ fixlist,
    float* __restrict__ f_all)
{
    int t = blockIdx.x * blockDim.x + threadIdx.x;
    unsigned fc = (unsigned)*fixcnt;
    if (fc > (unsigned)FIXCAP) fc = FIXCAP;
    if ((unsigned)t >= fc) return;
    int P = fixlist[t] & (NPTS - 1);
    int r = P & (NR - 1), s = P >> 16;
    float d = ((float)s * (1.0f / 15.0f)) * FARV;
    float ox = ray0[3 * r], oy = ray0[3 * r + 1], oz = ray0[3 * r + 2];
    float dx = dirs[3 * r], dy = dirs[3 * r + 1], dz = dirs[3 * r + 2];
    const float* cv = cva + (r >> 14) * H;
    f_all[P] = mlp_eval(fmaf(d, dx, ox), fmaf(d, dy, oy), fmaf(d, dz, oz),
                        W1, cv, W2, b2, W3, *b3p);
}

// ---------------- crossing scan --------------------------------------------
__global__ void k_cross(
    const float* __restrict__ ray0, const float* __restrict__ dirs,
    const float* __restrict__ f_all,
    int* __restrict__ count, int* __restrict__ ids,
    float4* __restrict__ state, float* __restrict__ out)
{
    int r = blockIdx.x * blockDim.x + threadIdx.x;   // 65536 threads
    float fv[NS];
#pragma unroll
    for (int s = 0; s < NS; ++s) fv[s] = f_all[s * NR + r];
    int idx = -1;
#pragma unroll
    for (int s = NS - 2; s >= 0; --s) {
        if (fv[s] < 0.0f && fv[s + 1] >= 0.0f) idx = s;
    }
    if (idx < 0) {
        float ox = ray0[3 * r], oy = ray0[3 * r + 1], oz = ray0[3 * r + 2];
        float dx = dirs[3 * r], dy = dirs[3 * r + 1], dz = dirs[3 * r + 2];
        out[r] = FARV;
        out[NR + 3 * r + 0] = fmaf(FARV, dx, ox);
        out[NR + 3 * r + 1] = fmaf(FARV, dy, oy);
        out[NR + 3 * r + 2] = fmaf(FARV, dz, oz);
        out[4 * NR + r] = 0.0f;
    } else {
        int slot = atomicAdd(count, 1);
        ids[slot] = r;
        float dlo = ((float)idx * (1.0f / 15.0f)) * FARV;
        float dhi = ((float)(idx + 1) * (1.0f / 15.0f)) * FARV;
        state[slot] = make_float4(dlo, 0.0f, dhi, 0.0f);   // f re-evaled in refine
    }
}

// ---------------- Phase B: MFMA secant refine (16 rays per block) ----------
// R13 structure + (R18) accumulator splitting: each output keeps 3
// independent accumulators (hi*Bh, lo*Bh, hi*Bl), cutting the dependent
// MFMA chain from 12 to 4 — refine is latency-bound, chain depth is the
// per-iteration critical path. Summation order change only (fp32 adds).
__global__ __launch_bounds__(256, 2) void k_refine(
    const float* __restrict__ ray0, const float* __restrict__ dirs,
    const float* __restrict__ W1,   const float* __restrict__ cva,
    const float* __restrict__ b2,   const float* __restrict__ W3,
    const float* __restrict__ b3p,  const short* __restrict__ w2f,
    const int* __restrict__ count,  const int* __restrict__ ids,
    const float4* __restrict__ state, float* __restrict__ out)
{
    __shared__ __align__(16) short hAhi[2048];       // 4 ks x 64 lanes x short8
    __shared__ __align__(16) short hAlo[2048];
    __shared__ float fpart[4][16];
    const int tid = threadIdx.x;
    const int w = tid >> 6, lane = tid & 63;
    const int q = lane >> 4, ln15 = lane & 15;

    unsigned cnt = (unsigned)*count;
    if (cnt > (unsigned)NR) cnt = (unsigned)NR;      // poison guard

    const short8* wf8 = (const short8*)w2f;
    short8 Bh0[4], Bl0[4], Bh1[4], Bl1[4];
#pragma unroll
    for (int ks = 0; ks < 4; ++ks) {
        Bh0[ks] = wf8[((w * 4 + 0) * 4 + ks) * 64 + lane];
        Bl0[ks] = wf8[((w * 4 + 1) * 4 + ks) * 64 + lane];
        Bh1[ks] = wf8[((w * 4 + 2) * 4 + ks) * 64 + lane];
        Bl1[ks] = wf8[((w * 4 + 3) * 4 + ks) * 64 + lane];
    }
    const float w3n0 = W3[w * 32 + ln15],      w3n1 = W3[w * 32 + 16 + ln15];
    const float b2n0 = b2[w * 32 + ln15],      b2n1 = b2[w * 32 + 16 + ln15];
    const float b3v  = *b3p;

    const int i4 = (w * 32 + q * 8) >> 2;
    const float4* W1x4 = (const float4*)(W1);
    const float4* W1y4 = (const float4*)(W1 + H);
    const float4* W1z4 = (const float4*)(W1 + 2 * H);
    const float4 x0 = W1x4[i4], x1 = W1x4[i4 + 1];
    const float4 y0 = W1y4[i4], y1 = W1y4[i4 + 1];
    const float4 z0 = W1z4[i4], z1 = W1z4[i4 + 1];

    uint4* hi4 = (uint4*)hAhi;
    uint4* lo4 = (uint4*)hAlo;
    const short8* hi8 = (const short8*)hAhi;
    const short8* lo8 = (const short8*)hAlo;

    for (unsigned g = blockIdx.x; g * 16u < cnt; g += gridDim.x) {
        unsigned t = g * 16u + (unsigned)ln15;
        bool valid = (t < cnt);
        unsigned tc = valid ? t : (cnt - 1);
        int r = ids[tc] & (NR - 1);                  // poison guard
        float4 st = state[tc];
        float dlo = st.x, dhi = st.z;
        float flo = 0.0f, fhi = 0.0f;
        float ox = ray0[3 * r], oy = ray0[3 * r + 1], oz = ray0[3 * r + 2];
        float dx = dirs[3 * r], dy = dirs[3 * r + 1], dz = dirs[3 * r + 2];
        const float4* cv4 = (const float4*)(cva + (r >> 14) * H);
        float4 c0 = cv4[i4], c1 = cv4[i4 + 1];
        float dp = 0.0f;

#pragma unroll 1
        for (int it = 0; it < 11; ++it) {
            // it 0: eval @dlo; it 1: eval @dhi; it 2..9: secant; it 10: final
            float dn;
            if (it >= 2) {
                float dc  = fhi - flo;
                float den = copysignf(fmaxf(fabsf(dc), EPSF), dc);
                dn  = dlo - (flo * (dhi - dlo)) / den;
                if (it == 10) { dp = dn; break; }
            } else {
                dn = (it == 0) ? dlo : dhi;
            }
            // stage 1: h for ray ln15, 8 k values -> hi/lo bf16 -> LDS
            float px = fmaf(dn, dx, ox), py = fmaf(dn, dy, oy), pz = fmaf(dn, dz, oz);
            float hv[8];
            hv[0] = fmaf(px, x0.x, fmaf(py, y0.x, fmaf(pz, z0.x, c0.x)));
            hv[1] = fmaf(px, x0.y, fmaf(py, y0.y, fmaf(pz, z0.y, c0.y)));
            hv[2] = fmaf(px, x0.z, fmaf(py, y0.z, fmaf(pz, z0.z, c0.z)));
            hv[3] = fmaf(px, x0.w, fmaf(py, y0.w, fmaf(pz, z0.w, c0.w)));
            hv[4] = fmaf(px, x1.x, fmaf(py, y1.x, fmaf(pz, z1.x, c1.x)));
            hv[5] = fmaf(px, x1.y, fmaf(py, y1.y, fmaf(pz, z1.y, c1.y)));
            hv[6] = fmaf(px, x1.z, fmaf(py, y1.z, fmaf(pz, z1.z, c1.z)));
            hv[7] = fmaf(px, x1.w, fmaf(py, y1.w, fmaf(pz, z1.w, c1.w)));
            unsigned uh[4], ul[4];
#pragma unroll
            for (int jp = 0; jp < 4; ++jp) {
                float h0 = fmaxf(hv[2 * jp],     0.0f);
                float h1 = fmaxf(hv[2 * jp + 1], 0.0f);
                unsigned u = pk_bf16(h0, h1);
                float hf0 = __uint_as_float(u << 16);
                float hf1 = __uint_as_float(u & 0xFFFF0000u);
                ul[jp] = pk_bf16(h0 - hf0, h1 - hf1);
                uh[jp] = u;
            }
            hi4[w * 64 + lane] = make_uint4(uh[0], uh[1], uh[2], uh[3]);
            lo4[w * 64 + lane] = make_uint4(ul[0], ul[1], ul[2], ul[3]);
            __syncthreads();
            // stage 2: MFMA, 3 independent 4-deep chains per output
            short8 Ah[4], Al[4];
#pragma unroll
            for (int ks = 0; ks < 4; ++ks) {
                Ah[ks] = hi8[ks * 64 + lane];
                Al[ks] = lo8[ks * 64 + lane];
            }
            f32x4 hh0 = {0.f, 0.f, 0.f, 0.f}, lh0 = {0.f, 0.f, 0.f, 0.f};
            f32x4 hl0 = {0.f, 0.f, 0.f, 0.f};
            f32x4 hh1 = {0.f, 0.f, 0.f, 0.f}, lh1 = {0.f, 0.f, 0.f, 0.f};
            f32x4 hl1 = {0.f, 0.f, 0.f, 0.f};
#pragma unroll
            for (int ks = 0; ks < 4; ++ks) {
                hh0 = __builtin_amdgcn_mfma_f32_16x16x32_bf16(Ah[ks], Bh0[ks], hh0, 0, 0, 0);
                hh1 = __builtin_amdgcn_mfma_f32_16x16x32_bf16(Ah[ks], Bh1[ks], hh1, 0, 0, 0);
                lh0 = __builtin_amdgcn_mfma_f32_16x16x32_bf16(Al[ks], Bh0[ks], lh0, 0, 0, 0);
                lh1 = __builtin_amdgcn_mfma_f32_16x16x32_bf16(Al[ks], Bh1[ks], lh1, 0, 0, 0);
                hl0 = __builtin_amdgcn_mfma_f32_16x16x32_bf16(Ah[ks], Bl0[ks], hl0, 0, 0, 0);
                hl1 = __builtin_amdgcn_mfma_f32_16x16x32_bf16(Ah[ks], Bl1[ks], hl1, 0, 0, 0);
            }
#pragma unroll
            for (int reg = 0; reg < 4; ++reg) {
                float a0 = (hh0[reg] + lh0[reg]) + hl0[reg];
                float a1 = (hh1[reg] + lh1[reg]) + hl1[reg];
                float v = fmaf(fmaxf(a0 + b2n0, 0.f), w3n0,
                               fmaxf(a1 + b2n1, 0.f) * w3n1);
                v = rowsum16(v);
                if (ln15 == 0) fpart[w][q * 4 + reg] = v;
            }
            __syncthreads();
            float fn = fpart[0][ln15] + fpart[1][ln15] + fpart[2][ln15]
                     + fpart[3][ln15] + b3v;
            if (it == 0)      { flo = fn; }
            else if (it == 1) { fhi = fn; }
            else {
                bool bel = (fn < 0.0f);
                dlo = bel ? dn  : dlo;  flo = bel ? fn  : flo;
                dhi = bel ? dhi : dn;   fhi = bel ? fhi : fn;
            }
        }
        if (tid < 16 && valid) {
            out[r] = dp;
            out[NR + 3 * r + 0] = fmaf(dp, dx, ox);
            out[NR + 3 * r + 1] = fmaf(dp, dy, oy);
            out[NR + 3 * r + 2] = fmaf(dp, dz, oz);
            out[4 * NR + r] = 1.0f;
        }
    }
}

// ---------------------------------------------------------------------------
extern "C" void kernel_launch(void* const* d_in, const int* in_sizes, int n_in,
                              void* d_out, int out_size, void* d_ws, size_t ws_size,
                              hipStream_t stream)
{
    const float* ray0 = (const float*)d_in[0];
    const float* dirs = (const float*)d_in[1];
    const float* feat = (const float*)d_in[2];
    const float* W1   = (const float*)d_in[3];
    const float* b1   = (const float*)d_in[4];
    const float* W2   = (const float*)d_in[5];
    const float* b2   = (const float*)d_in[6];
    const float* W3   = (const float*)d_in[7];
    const float* b3   = (const float*)d_in[8];
    float* out = (float*)d_out;

    // workspace layout (float offsets), total ~6.1 MB
    float* w      = (float*)d_ws;
    short* w2f    = (short*)w;                        // 32768 bf16 = 16384 f
    float* cva    = w + 16384;                        // 512
    float* f_all  = w + 16896;                        // 1,048,576
    float* stf    = w + 1065472;                      // 262,144 (16B aligned)
    int*   ids    = (int*)(w + 1327616);              // 65,536
    int*   fixlist= (int*)(w + 1393152);              // 131,072
    int*   count  = (int*)(w + 1524224);
    int*   fixcnt = (int*)(w + 1524225);

    k_setup <<<16,   256, 0, stream>>>(W1, b1, W2, feat, cva, w2f, count, fixcnt);
    k_marchx<<<512,  256, 0, stream>>>(ray0, dirs, W1, cva, b2, W3, b3, w2f,
                                       f_all, fixlist, fixcnt);
    k_fix   <<<FIXCAP / 256, 256, 0, stream>>>(ray0, dirs, W1, cva, W2, b2, W3, b3,
                                               fixcnt, fixlist, f_all);
    k_cross <<<NR / 256, 256, 0, stream>>>(ray0, dirs, f_all, count, ids,
                                           (float4*)stf, out);
    k_refine<<<1280, 256, 0, stream>>>(ray0, dirs, W1, cva, b2, W3, b3, w2f,
                                       count, ids, (const float4*)stf, out);
}

// Round 19
// 275.082 us; speedup vs baseline: 1.0109x; 1.0069x over previous
//
#include <hip/hip_runtime.h>
#include <hip/hip_bf16.h>

typedef short short8 __attribute__((ext_vector_type(8)));
typedef float f32x4  __attribute__((ext_vector_type(4)));

static constexpr int   NPB  = 16384;
static constexpr int   NR   = 4 * NPB;       // 65536 rays
static constexpr int   NS   = 16;
static constexpr int   H    = 128;
static constexpr int   NPTS = NR * NS;       // 1,048,576 march points
static constexpr int   NCHUNK2 = NPTS / 128; // 8192 chunks of 128 points
static constexpr int   FIXCAP = 131072;
static constexpr float FARV = 2.4f;
static constexpr float EPSF = 1.1920928955078125e-07f;
// march f error with A=bf16-RNE only (W2 hi+lo): RMS ~1e-3, worst ~0.03.
// R9/R13 proved this config correctness-safe at FTHRESH=0.03.
static constexpr float FTHRESH = 0.03f;

// NOTE (R12): never declare __launch_bounds__ > 2 waves/EU on MFMA kernels.
// NOTE (R14): refine groups must outnumber blocks.
// NOTE (R15): do NOT interleave stage1(c+1) VALU with stage2(c) MFMA.
// NOTE (R17/R18): extra barrier removal, mt-unroll, accumulator-split all
// neutral — compiler schedule already optimal; residual idle is barrier-drain.

// ---------------- bf16 helpers ---------------------------------------------
__device__ __forceinline__ unsigned bf16hi(float x) {
    unsigned u = __float_as_uint(x);
    return (u + 0x7FFFu + ((u >> 16) & 1u)) >> 16;
}
__device__ __forceinline__ void split_bf16(float x, short& hi, short& lo) {
    unsigned h = bf16hi(x);
    float hf = __uint_as_float(h << 16);
    unsigned l = __float_as_uint(x - hf) >> 16;
    hi = (short)h; lo = (short)l;
}
// packed RNE f32x2 -> bf16x2 (v_cvt_pk_bf16_f32 on gfx950)
__device__ __forceinline__ unsigned pk_bf16(float a, float b) {
    __hip_bfloat162 p = __float22bfloat162_rn(make_float2(a, b));
    unsigned u;
    __builtin_memcpy(&u, &p, sizeof(u));
    return u;
}

// DPP row-rotate sum over 16-lane rows (pure VALU pipe)
__device__ __forceinline__ float rowsum16(float v) {
    v += __int_as_float(__builtin_amdgcn_update_dpp(0, __float_as_int(v), 0x128, 0xF, 0xF, true));
    v += __int_as_float(__builtin_amdgcn_update_dpp(0, __float_as_int(v), 0x124, 0xF, 0xF, true));
    v += __int_as_float(__builtin_amdgcn_update_dpp(0, __float_as_int(v), 0x122, 0xF, 0xF, true));
    v += __int_as_float(__builtin_amdgcn_update_dpp(0, __float_as_int(v), 0x121, 0xF, 0xF, true));
    return v;
}

// ---------------- exact fp32 thread-per-point MLP (for fixups) -------------
__device__ __forceinline__ float mlp_eval(
    float px, float py, float pz,
    const float* __restrict__ W1, const float* __restrict__ cv,
    const float* __restrict__ W2, const float* __restrict__ b2,
    const float* __restrict__ W3, float b3v)
{
    float f = b3v;
#pragma unroll 1
    for (int p = 0; p < 2; ++p) {
        const float* __restrict__ b2p = b2 + p * 64;
        const float* __restrict__ W3p = W3 + p * 64;
        float a[64];
#pragma unroll
        for (int j = 0; j < 64; ++j) a[j] = b2p[j];
#pragma unroll 2
        for (int k = 0; k < H; ++k) {
            float hk = cv[k];
            hk = fmaf(px, W1[k], hk);
            hk = fmaf(py, W1[H + k], hk);
            hk = fmaf(pz, W1[2 * H + k], hk);
            hk = fmaxf(hk, 0.0f);
            const float* __restrict__ w = W2 + k * H + p * 64;
#pragma unroll
            for (int j = 0; j < 64; ++j) a[j] = fmaf(hk, w[j], a[j]);
        }
#pragma unroll
        for (int j = 0; j < 64; ++j)
            f = fmaf(fmaxf(a[j], 0.0f), W3p[j], f);
    }
    return f;
}

// ---------------- setup: cv vectors + W2 MFMA packing + counters -----------
__global__ void k_setup(const float* __restrict__ W1, const float* __restrict__ b1,
                        const float* __restrict__ W2, const float* __restrict__ feat,
                        float* __restrict__ cva, short* __restrict__ w2f,
                        int* __restrict__ count, int* __restrict__ fixcnt)
{
    int t = blockIdx.x * blockDim.x + threadIdx.x;   // 4096 threads
    if (t == 0) { *count = 0; *fixcnt = 0; }
    if (t < 4 * H) {                                 // cv = b1 + feat @ W1[3:35]
        int b = t >> 7, kk = t & (H - 1);
        float acc = b1[kk];
#pragma unroll
        for (int i = 0; i < 32; ++i)
            acc = fmaf(feat[b * 32 + i], W1[(3 + i) * H + kk], acc);
        cva[b * H + kk] = acc;
    }
    {                                                // MFMA B-fragments (hi/lo)
        int lane = t & 63, ks = (t >> 6) & 3, part = (t >> 8) & 1;
        int nt = (t >> 9) & 1, w = (t >> 10) & 3;
        int n = w * 32 + nt * 16 + (lane & 15);
        int kb = ks * 32 + (lane >> 4) * 8;
        short8 v;
#pragma unroll
        for (int j = 0; j < 8; ++j) {
            short hi, lo;
            split_bf16(W2[(kb + j) * H + n], hi, lo);
            v[j] = part ? lo : hi;
        }
        ((short8*)w2f)[((w * 4 + nt * 2 + part) * 4 + ks) * 64 + lane] = v;
    }
}

// ---------------- Phase A: MFMA march (128 points per chunk) ---------------
// R13 numerics; (R19) 128-pt chunks halve barrier count per point. Each wave
// stage1-computes 2 point-groups (both inside stage 1 — no cross-stage
// interleave), stage2 runs 8 M-tiles per barrier pair.
__global__ __launch_bounds__(256, 2) void k_marchx(
    const float* __restrict__ ray0, const float* __restrict__ dirs,
    const float* __restrict__ W1,   const float* __restrict__ cva,
    const float* __restrict__ b2,   const float* __restrict__ W3,
    const float* __restrict__ b3p,  const short* __restrict__ w2f,
    float* __restrict__ f_all, int* __restrict__ fixlist, int* __restrict__ fixcnt)
{
    __shared__ __align__(16) short hAhi[16384];      // 128 pts x 128 k (32 KB)
    __shared__ float fpart[2][4][128];               // ping-pong
    const int tid = threadIdx.x;
    const int w = tid >> 6, lane = tid & 63;
    const int q = lane >> 4, ln15 = lane & 15;

    const short8* wf8 = (const short8*)w2f;
    short8 Bh0[4], Bl0[4], Bh1[4], Bl1[4];
#pragma unroll
    for (int ks = 0; ks < 4; ++ks) {
        Bh0[ks] = wf8[((w * 4 + 0) * 4 + ks) * 64 + lane];
        Bl0[ks] = wf8[((w * 4 + 1) * 4 + ks) * 64 + lane];
        Bh1[ks] = wf8[((w * 4 + 2) * 4 + ks) * 64 + lane];
        Bl1[ks] = wf8[((w * 4 + 3) * 4 + ks) * 64 + lane];
    }
    const float w3n0 = W3[w * 32 + ln15],      w3n1 = W3[w * 32 + 16 + ln15];
    const float b2n0 = b2[w * 32 + ln15],      b2n1 = b2[w * 32 + 16 + ln15];
    const float b3v  = *b3p;
    const float4* W1x4 = (const float4*)(W1);
    const float4* W1y4 = (const float4*)(W1 + H);
    const float4* W1z4 = (const float4*)(W1 + 2 * H);

    int pp = 0;
    for (int c = blockIdx.x; c < NCHUNK2; c += gridDim.x) {
        // ---- stage 1: h (fp32) -> RNE bf16 -> LDS, 2 point-groups per wave
        uint4* hi4 = (uint4*)hAhi;
#pragma unroll 1
        for (int half = 0; half < 2; ++half) {
            int m = half * 64 + w * 16 + ln15;
            int P = c * 128 + m;
            int r = P & (NR - 1), s = P >> 16;
            float d = ((float)s * (1.0f / 15.0f)) * FARV;
            float ox = ray0[3 * r], oy = ray0[3 * r + 1], oz = ray0[3 * r + 2];
            float dx = dirs[3 * r], dy = dirs[3 * r + 1], dz = dirs[3 * r + 2];
            float px = fmaf(d, dx, ox), py = fmaf(d, dy, oy), pz = fmaf(d, dz, oz);
            const float4* cv4 = (const float4*)(cva + (((c * 128) & (NR - 1)) >> 14) * H);
#pragma unroll
            for (int ks = 0; ks < 4; ++ks) {
                int i4 = (ks * 32 + q * 8) >> 2;
                float4 x0 = W1x4[i4], x1 = W1x4[i4 + 1];
                float4 y0 = W1y4[i4], y1 = W1y4[i4 + 1];
                float4 z0 = W1z4[i4], z1 = W1z4[i4 + 1];
                float4 c0 = cv4[i4],  c1 = cv4[i4 + 1];
                float hv[8];
                hv[0] = fmaf(px, x0.x, fmaf(py, y0.x, fmaf(pz, z0.x, c0.x)));
                hv[1] = fmaf(px, x0.y, fmaf(py, y0.y, fmaf(pz, z0.y, c0.y)));
                hv[2] = fmaf(px, x0.z, fmaf(py, y0.z, fmaf(pz, z0.z, c0.z)));
                hv[3] = fmaf(px, x0.w, fmaf(py, y0.w, fmaf(pz, z0.w, c0.w)));
                hv[4] = fmaf(px, x1.x, fmaf(py, y1.x, fmaf(pz, z1.x, c1.x)));
                hv[5] = fmaf(px, x1.y, fmaf(py, y1.y, fmaf(pz, z1.y, c1.y)));
                hv[6] = fmaf(px, x1.z, fmaf(py, y1.z, fmaf(pz, z1.z, c1.z)));
                hv[7] = fmaf(px, x1.w, fmaf(py, y1.w, fmaf(pz, z1.w, c1.w)));
                unsigned uh[4];
#pragma unroll
                for (int jp = 0; jp < 4; ++jp)
                    uh[jp] = pk_bf16(fmaxf(hv[2 * jp],     0.0f),
                                     fmaxf(hv[2 * jp + 1], 0.0f));
                hi4[((half * 4 + w) * 4 + ks) * 64 + lane] =
                    make_uint4(uh[0], uh[1], uh[2], uh[3]);
            }
        }
        __syncthreads();
        // ---- stage 2: MFMA per 16-point M-tile (8 tiles) + epilogue
        const short8* hi8 = (const short8*)hAhi;
#pragma unroll 2
        for (int mt = 0; mt < 8; ++mt) {
            short8 Ah[4];
#pragma unroll
            for (int ks = 0; ks < 4; ++ks)
                Ah[ks] = hi8[(mt * 4 + ks) * 64 + lane];
            f32x4 a0 = {0.f, 0.f, 0.f, 0.f}, a1 = {0.f, 0.f, 0.f, 0.f};
#pragma unroll
            for (int ks = 0; ks < 4; ++ks) {
                a0 = __builtin_amdgcn_mfma_f32_16x16x32_bf16(Ah[ks], Bh0[ks], a0, 0, 0, 0);
                a1 = __builtin_amdgcn_mfma_f32_16x16x32_bf16(Ah[ks], Bh1[ks], a1, 0, 0, 0);
                a0 = __builtin_amdgcn_mfma_f32_16x16x32_bf16(Ah[ks], Bl0[ks], a0, 0, 0, 0);
                a1 = __builtin_amdgcn_mfma_f32_16x16x32_bf16(Ah[ks], Bl1[ks], a1, 0, 0, 0);
            }
#pragma unroll
            for (int reg = 0; reg < 4; ++reg) {
                float v = fmaf(fmaxf(a0[reg] + b2n0, 0.f), w3n0,
                               fmaxf(a1[reg] + b2n1, 0.f) * w3n1);
                v = rowsum16(v);
                if (ln15 == 0) fpart[pp][w][mt * 16 + q * 4 + reg] = v;
            }
        }
        __syncthreads();
        // ---- stage 3: finalize 128 points (fpart ping-pong: no 3rd barrier)
        if (tid < 128) {
            float f = fpart[pp][0][tid] + fpart[pp][1][tid] + fpart[pp][2][tid]
                    + fpart[pp][3][tid] + b3v;
            int P = c * 128 + tid;
            f_all[P] = f;
            if (fabsf(f) < FTHRESH) {
                int s = atomicAdd(fixcnt, 1);
                if (s < FIXCAP) fixlist[s] = P;
            }
        }
        pp ^= 1;
    }
}

// ---------------- fp32 re-eval of near-zero points -------------------------
__global__ __launch_bounds__(256, 2) void k_fix(
    const float* __restrict__ ray0, const float* __restrict__ dirs,
    const float* __restrict__ W1,   const float* __restrict__ cva,
    const float* __restrict__ W2,   const float* __restrict__ b2,
    const float* __restrict__ W3,   const float* __restrict__ b3p,
    const int* __restrict__ fixcnt, const int* __restrict__ fixlist,
    float* __restrict__ f_all)
{
    int t = blockIdx.x * blockDim.x + threadIdx.x;
    unsigned fc = (unsigned)*fixcnt;
    if (fc > (unsigned)FIXCAP) fc = FIXCAP;
    if ((unsigned)t >= fc) return;
    int P = fixlist[t] & (NPTS - 1);
    int r = P & (NR - 1), s = P >> 16;
    float d = ((float)s * (1.0f / 15.0f)) * FARV;
    float ox = ray0[3 * r], oy = ray0[3 * r + 1], oz = ray0[3 * r + 2];
    float dx = dirs[3 * r], dy = dirs[3 * r + 1], dz = dirs[3 * r + 2];
    const float* cv = cva + (r >> 14) * H;
    f_all[P] = mlp_eval(fmaf(d, dx, ox), fmaf(d, dy, oy), fmaf(d, dz, oz),
                        W1, cv, W2, b2, W3, *b3p);
}

// ---------------- crossing scan --------------------------------------------
__global__ void k_cross(
    const float* __restrict__ ray0, const float* __restrict__ dirs,
    const float* __restrict__ f_all,
    int* __restrict__ count, int* __restrict__ ids,
    float4* __restrict__ state, float* __restrict__ out)
{
    int r = blockIdx.x * blockDim.x + threadIdx.x;   // 65536 threads
    float fv[NS];
#pragma unroll
    for (int s = 0; s < NS; ++s) fv[s] = f_all[s * NR + r];
    int idx = -1;
#pragma unroll
    for (int s = NS - 2; s >= 0; --s) {
        if (fv[s] < 0.0f && fv[s + 1] >= 0.0f) idx = s;
    }
    if (idx < 0) {
        float ox = ray0[3 * r], oy = ray0[3 * r + 1], oz = ray0[3 * r + 2];
        float dx = dirs[3 * r], dy = dirs[3 * r + 1], dz = dirs[3 * r + 2];
        out[r] = FARV;
        out[NR + 3 * r + 0] = fmaf(FARV, dx, ox);
        out[NR + 3 * r + 1] = fmaf(FARV, dy, oy);
        out[NR + 3 * r + 2] = fmaf(FARV, dz, oz);
        out[4 * NR + r] = 0.0f;
    } else {
        int slot = atomicAdd(count, 1);
        ids[slot] = r;
        float dlo = ((float)idx * (1.0f / 15.0f)) * FARV;
        float dhi = ((float)(idx + 1) * (1.0f / 15.0f)) * FARV;
        state[slot] = make_float4(dlo, 0.0f, dhi, 0.0f);   // f re-evaled in refine
    }
}

// ---------------- Phase B: MFMA secant refine (16 rays per block) ----------
// R13 structure + R18 accumulator split (neutral but harmless). 6-MFMA eval
// (err ~3e-5); brackets re-evaluated here (it=0,1). Grid 1280.
__global__ __launch_bounds__(256, 2) void k_refine(
    const float* __restrict__ ray0, const float* __restrict__ dirs,
    const float* __restrict__ W1,   const float* __restrict__ cva,
    const float* __restrict__ b2,   const float* __restrict__ W3,
    const float* __restrict__ b3p,  const short* __restrict__ w2f,
    const int* __restrict__ count,  const int* __restrict__ ids,
    const float4* __restrict__ state, float* __restrict__ out)
{
    __shared__ __align__(16) short hAhi[2048];       // 4 ks x 64 lanes x short8
    __shared__ __align__(16) short hAlo[2048];
    __shared__ float fpart[4][16];
    const int tid = threadIdx.x;
    const int w = tid >> 6, lane = tid & 63;
    const int q = lane >> 4, ln15 = lane & 15;

    unsigned cnt = (unsigned)*count;
    if (cnt > (unsigned)NR) cnt = (unsigned)NR;      // poison guard

    const short8* wf8 = (const short8*)w2f;
    short8 Bh0[4], Bl0[4], Bh1[4], Bl1[4];
#pragma unroll
    for (int ks = 0; ks < 4; ++ks) {
        Bh0[ks] = wf8[((w * 4 + 0) * 4 + ks) * 64 + lane];
        Bl0[ks] = wf8[((w * 4 + 1) * 4 + ks) * 64 + lane];
        Bh1[ks] = wf8[((w * 4 + 2) * 4 + ks) * 64 + lane];
        Bl1[ks] = wf8[((w * 4 + 3) * 4 + ks) * 64 + lane];
    }
    const float w3n0 = W3[w * 32 + ln15],      w3n1 = W3[w * 32 + 16 + ln15];
    const float b2n0 = b2[w * 32 + ln15],      b2n1 = b2[w * 32 + 16 + ln15];
    const float b3v  = *b3p;

    const int i4 = (w * 32 + q * 8) >> 2;
    const float4* W1x4 = (const float4*)(W1);
    const float4* W1y4 = (const float4*)(W1 + H);
    const float4* W1z4 = (const float4*)(W1 + 2 * H);
    const float4 x0 = W1x4[i4], x1 = W1x4[i4 + 1];
    const float4 y0 = W1y4[i4], y1 = W1y4[i4 + 1];
    const float4 z0 = W1z4[i4], z1 = W1z4[i4 + 1];

    uint4* hi4 = (uint4*)hAhi;
    uint4* lo4 = (uint4*)hAlo;
    const short8* hi8 = (const short8*)hAhi;
    const short8* lo8 = (const short8*)hAlo;

    for (unsigned g = blockIdx.x; g * 16u < cnt; g += gridDim.x) {
        unsigned t = g * 16u + (unsigned)ln15;
        bool valid = (t < cnt);
        unsigned tc = valid ? t : (cnt - 1);
        int r = ids[tc] & (NR - 1);                  // poison guard
        float4 st = state[tc];
        float dlo = st.x, dhi = st.z;
        float flo = 0.0f, fhi = 0.0f;
        float ox = ray0[3 * r], oy = ray0[3 * r + 1], oz = ray0[3 * r + 2];
        float dx = dirs[3 * r], dy = dirs[3 * r + 1], dz = dirs[3 * r + 2];
        const float4* cv4 = (const float4*)(cva + (r >> 14) * H);
        float4 c0 = cv4[i4], c1 = cv4[i4 + 1];
        float dp = 0.0f;

#pragma unroll 1
        for (int it = 0; it < 11; ++it) {
            // it 0: eval @dlo; it 1: eval @dhi; it 2..9: secant; it 10: final
            float dn;
            if (it >= 2) {
                float dc  = fhi - flo;
                float den = copysignf(fmaxf(fabsf(dc), EPSF), dc);
                dn  = dlo - (flo * (dhi - dlo)) / den;
                if (it == 10) { dp = dn; break; }
            } else {
                dn = (it == 0) ? dlo : dhi;
            }
            // stage 1: h for ray ln15, 8 k values -> hi/lo bf16 -> LDS
            float px = fmaf(dn, dx, ox), py = fmaf(dn, dy, oy), pz = fmaf(dn, dz, oz);
            float hv[8];
            hv[0] = fmaf(px, x0.x, fmaf(py, y0.x, fmaf(pz, z0.x, c0.x)));
            hv[1] = fmaf(px, x0.y, fmaf(py, y0.y, fmaf(pz, z0.y, c0.y)));
            hv[2] = fmaf(px, x0.z, fmaf(py, y0.z, fmaf(pz, z0.z, c0.z)));
            hv[3] = fmaf(px, x0.w, fmaf(py, y0.w, fmaf(pz, z0.w, c0.w)));
            hv[4] = fmaf(px, x1.x, fmaf(py, y1.x, fmaf(pz, z1.x, c1.x)));
            hv[5] = fmaf(px, x1.y, fmaf(py, y1.y, fmaf(pz, z1.y, c1.y)));
            hv[6] = fmaf(px, x1.z, fmaf(py, y1.z, fmaf(pz, z1.z, c1.z)));
            hv[7] = fmaf(px, x1.w, fmaf(py, y1.w, fmaf(pz, z1.w, c1.w)));
            unsigned uh[4], ul[4];
#pragma unroll
            for (int jp = 0; jp < 4; ++jp) {
                float h0 = fmaxf(hv[2 * jp],     0.0f);
                float h1 = fmaxf(hv[2 * jp + 1], 0.0f);
                unsigned u = pk_bf16(h0, h1);
                float hf0 = __uint_as_float(u << 16);
                float hf1 = __uint_as_float(u & 0xFFFF0000u);
                ul[jp] = pk_bf16(h0 - hf0, h1 - hf1);
                uh[jp] = u;
            }
            hi4[w * 64 + lane] = make_uint4(uh[0], uh[1], uh[2], uh[3]);
            lo4[w * 64 + lane] = make_uint4(ul[0], ul[1], ul[2], ul[3]);
            __syncthreads();
            // stage 2: MFMA, 3 independent 4-deep chains per output
            short8 Ah[4], Al[4];
#pragma unroll
            for (int ks = 0; ks < 4; ++ks) {
                Ah[ks] = hi8[ks * 64 + lane];
                Al[ks] = lo8[ks * 64 + lane];
            }
            f32x4 hh0 = {0.f, 0.f, 0.f, 0.f}, lh0 = {0.f, 0.f, 0.f, 0.f};
            f32x4 hl0 = {0.f, 0.f, 0.f, 0.f};
            f32x4 hh1 = {0.f, 0.f, 0.f, 0.f}, lh1 = {0.f, 0.f, 0.f, 0.f};
            f32x4 hl1 = {0.f, 0.f, 0.f, 0.f};
#pragma unroll
            for (int ks = 0; ks < 4; ++ks) {
                hh0 = __builtin_amdgcn_mfma_f32_16x16x32_bf16(Ah[ks], Bh0[ks], hh0, 0, 0, 0);
                hh1 = __builtin_amdgcn_mfma_f32_16x16x32_bf16(Ah[ks], Bh1[ks], hh1, 0, 0, 0);
                lh0 = __builtin_amdgcn_mfma_f32_16x16x32_bf16(Al[ks], Bh0[ks], lh0, 0, 0, 0);
                lh1 = __builtin_amdgcn_mfma_f32_16x16x32_bf16(Al[ks], Bh1[ks], lh1, 0, 0, 0);
                hl0 = __builtin_amdgcn_mfma_f32_16x16x32_bf16(Ah[ks], Bl0[ks], hl0, 0, 0, 0);
                hl1 = __builtin_amdgcn_mfma_f32_16x16x32_bf16(Ah[ks], Bl1[ks], hl1, 0, 0, 0);
            }
#pragma unroll
            for (int reg = 0; reg < 4; ++reg) {
                float a0 = (hh0[reg] + lh0[reg]) + hl0[reg];
                float a1 = (hh1[reg] + lh1[reg]) + hl1[reg];
                float v = fmaf(fmaxf(a0 + b2n0, 0.f), w3n0,
                               fmaxf(a1 + b2n1, 0.f) * w3n1);
                v = rowsum16(v);
                if (ln15 == 0) fpart[w][q * 4 + reg] = v;
            }
            __syncthreads();
            float fn = fpart[0][ln15] + fpart[1][ln15] + fpart[2][ln15]
                     + fpart[3][ln15] + b3v;
            if (it == 0)      { flo = fn; }
            else if (it == 1) { fhi = fn; }
            else {
                bool bel = (fn < 0.0f);
                dlo = bel ? dn  : dlo;  flo = bel ? fn  : flo;
                dhi = bel ? dhi : dn;   fhi = bel ? fhi : fn;
            }
        }
        if (tid < 16 && valid) {
            out[r] = dp;
            out[NR + 3 * r + 0] = fmaf(dp, dx, ox);
            out[NR + 3 * r + 1] = fmaf(dp, dy, oy);
            out[NR + 3 * r + 2] = fmaf(dp, dz, oz);
            out[4 * NR + r] = 1.0f;
        }
    }
}

// ---------------------------------------------------------------------------
extern "C" void kernel_launch(void* const* d_in, const int* in_sizes, int n_in,
                              void* d_out, int out_size, void* d_ws, size_t ws_size,
                              hipStream_t stream)
{
    const float* ray0 = (const float*)d_in[0];
    const float* dirs = (const float*)d_in[1];
    const float* feat = (const float*)d_in[2];
    const float* W1   = (const float*)d_in[3];
    const float* b1   = (const float*)d_in[4];
    const float* W2   = (const float*)d_in[5];
    const float* b2   = (const float*)d_in[6];
    const float* W3   = (const float*)d_in[7];
    const float* b3   = (const float*)d_in[8];
    float* out = (float*)d_out;

    // workspace layout (float offsets), total ~6.1 MB
    float* w      = (float*)d_ws;
    short* w2f    = (short*)w;                        // 32768 bf16 = 16384 f
    float* cva    = w + 16384;                        // 512
    float* f_all  = w + 16896;                        // 1,048,576
    float* stf    = w + 1065472;                      // 262,144 (16B aligned)
    int*   ids    = (int*)(w + 1327616);              // 65,536
    int*   fixlist= (int*)(w + 1393152);              // 131,072
    int*   count  = (int*)(w + 1524224);
    int*   fixcnt = (int*)(w + 1524225);

    k_setup <<<16,   256, 0, stream>>>(W1, b1, W2, feat, cva, w2f, count, fixcnt);
    k_marchx<<<512,  256, 0, stream>>>(ray0, dirs, W1, cva, b2, W3, b3, w2f,
                                       f_all, fixlist, fixcnt);
    k_fix   <<<FIXCAP / 256, 256, 0, stream>>>(ray0, dirs, W1, cva, W2, b2, W3, b3,
                                               fixcnt, fixlist, f_all);
    k_cross <<<NR / 256, 256, 0, stream>>>(ray0, dirs, f_all, count, ids,
                                           (float4*)stf, out);
    k_refine<<<1280, 256, 0, stream>>>(ray0, dirs, W1, cva, b2, W3, b3, w2f,
                                       count, ids, (const float4*)stf, out);
}